// Round 2
// baseline (650.025 us; speedup 1.0000x reference)
//
#include <hip/hip_runtime.h>
#include <hip/hip_bf16.h>
#include <type_traits>

using bf16 = __hip_bfloat16;
typedef __attribute__((ext_vector_type(8))) short short8;   // 8 bf16 = 4 VGPRs (A/B frag)
typedef __attribute__((ext_vector_type(4))) float floatx4;  // C/D frag

struct alignas(16) bf16x8 { bf16 v[8]; };

#define EPSV 1e-5f

__device__ __forceinline__ float lrelu(float v) { return v >= 0.f ? v : 0.2f * v; }

// convert 8 contiguous f32 -> 8 bf16 packed in a uint4
__device__ __forceinline__ uint4 f8_to_bf8(const float* __restrict__ p) {
    float4 a = ((const float4*)p)[0];
    float4 b = ((const float4*)p)[1];
    bf16x8 r;
    r.v[0] = __float2bfloat16(a.x); r.v[1] = __float2bfloat16(a.y);
    r.v[2] = __float2bfloat16(a.z); r.v[3] = __float2bfloat16(a.w);
    r.v[4] = __float2bfloat16(b.x); r.v[5] = __float2bfloat16(b.y);
    r.v[6] = __float2bfloat16(b.z); r.v[7] = __float2bfloat16(b.w);
    return *(uint4*)&r;
}

// ---------------------------------------------------------------------------
// Copy f0..f3 -> out regions 0..3 (bit-exact f32 passthrough). 8 f32/thread.
// grid (4096, 4), block 256
__global__ __launch_bounds__(256) void copy4_k(
    const float* __restrict__ f0, const float* __restrict__ f1,
    const float* __restrict__ f2, const float* __restrict__ f3,
    float* __restrict__ out)
{
    int region = blockIdx.y;
    const float* src = (region == 0) ? f0 : (region == 1) ? f1 : (region == 2) ? f2 : f3;
    size_t off = ((size_t)blockIdx.x * 256 + threadIdx.x) * 8;
    float* dst = out + (size_t)region * 8388608 + off;
    ((uint4*)dst)[0] = ((const uint4*)(src + off))[0];
    ((uint4*)dst)[1] = ((const uint4*)(src + off))[1];
}

// ---------------------------------------------------------------------------
// Index chains. grid 64, block 128.
// rowidx layout: [5][8192]; slots 0..3 = gathered row ids for f0..f3, slot 4 = identity.
__global__ void idx_k(const int* __restrict__ FPS0, const int* __restrict__ FPS1,
                      const int* __restrict__ FPS2, const int* __restrict__ FPS3,
                      int* __restrict__ rowidx)
{
    int b = blockIdx.x;    // 64
    int s = threadIdx.x;   // 128
    int i3 = FPS3[b * 128 + s];    // [0,256)
    int i2 = FPS2[b * 256 + i3];   // [0,512)
    int i1 = FPS1[b * 512 + i2];   // [0,1024)
    int i0 = FPS0[b * 1024 + i1];  // [0,2048)
    int m = b * 128 + s;
    rowidx[0 * 8192 + m] = b * 2048 + i0;
    rowidx[1 * 8192 + m] = b * 1024 + i1;
    rowidx[2 * 8192 + m] = b * 512 + i2;
    rowidx[3 * 8192 + m] = b * 256 + i3;
    rowidx[4 * 8192 + m] = m;
}

// ---------------------------------------------------------------------------
// GEMM: Y[m,n] = sum_k A[rowidx[m], k] * W[n, k]   (TN, both K-contiguous)
// A: f32 or bf16 [*, K] rows selected by rowidx; W: f32 [1024, K]; Y: bf16 [8192, 1024]
// f32 operands are converted to bf16 during LDS staging (harness tolerance is
// bf16-floor, 8 eps). Block 256 thr = 4 waves (2x2), tile 128x128, BK=32.
// grid (64, 8)
template <typename AT>
__global__ __launch_bounds__(256) void gemm_bt(
    const AT* __restrict__ A, const float* __restrict__ W,
    bf16* __restrict__ Y, const int* __restrict__ rowidx, int K)
{
    __shared__ bf16 As[128][40];   // +8 pad: stride 80B -> only 2-way bank alias (free)
    __shared__ bf16 Bs[128][40];

    int tid = threadIdx.x;
    int bm = blockIdx.x, bn = blockIdx.y;

    // staging assignments: each thread loads 2 rows x 8 elements per tile per operand
    int r0 = tid >> 2;               // 0..63
    int r1 = r0 + 64;                // 64..127
    int c0 = (tid & 3) << 3;         // 0,8,16,24 (elements)
    const AT* a0 = A + (size_t)rowidx[bm * 128 + r0] * K + c0;
    const AT* a1 = A + (size_t)rowidx[bm * 128 + r1] * K + c0;
    const float* b0 = W + (size_t)(bn * 128 + r0) * K + c0;
    const float* b1 = W + (size_t)(bn * 128 + r1) * K + c0;

    int lane = tid & 63, wave = tid >> 6;
    int wm = (wave >> 1) << 6;       // wave M origin within tile (0/64)
    int wn = (wave & 1) << 6;        // wave N origin within tile (0/64)
    int lm = lane & 15;              // A row / B col within 16-tile
    int kq = (lane >> 4) << 3;       // k quad offset (0/8/16/24)

    floatx4 acc[4][4] = {};

    for (int k0 = 0; k0 < K; k0 += 32) {
        if constexpr (std::is_same<AT, float>::value) {
            *(uint4*)&As[r0][c0] = f8_to_bf8(a0 + k0);
            *(uint4*)&As[r1][c0] = f8_to_bf8(a1 + k0);
        } else {
            *(uint4*)&As[r0][c0] = *(const uint4*)(a0 + k0);
            *(uint4*)&As[r1][c0] = *(const uint4*)(a1 + k0);
        }
        *(uint4*)&Bs[r0][c0] = f8_to_bf8(b0 + k0);
        *(uint4*)&Bs[r1][c0] = f8_to_bf8(b1 + k0);
        __syncthreads();

        short8 af[4], bfr[4];
#pragma unroll
        for (int i = 0; i < 4; i++) af[i]  = *(const short8*)&As[wm + i * 16 + lm][kq];
#pragma unroll
        for (int j = 0; j < 4; j++) bfr[j] = *(const short8*)&Bs[wn + j * 16 + lm][kq];
#pragma unroll
        for (int i = 0; i < 4; i++)
#pragma unroll
            for (int j = 0; j < 4; j++)
                acc[i][j] = __builtin_amdgcn_mfma_f32_16x16x32_bf16(af[i], bfr[j], acc[i][j], 0, 0, 0);
        __syncthreads();
    }

    // epilogue: C/D layout col=lane&15, row=quad*4+reg  (verified m89/m91)
    int mrow = (lane >> 4) << 2;
    int ncol = lane & 15;
#pragma unroll
    for (int i = 0; i < 4; i++) {
#pragma unroll
        for (int j = 0; j < 4; j++) {
#pragma unroll
            for (int r = 0; r < 4; r++) {
                int m = (bm << 7) + wm + i * 16 + mrow + r;
                int n = (bn << 7) + wn + j * 16 + ncol;
                Y[(size_t)m * 1024 + n] = __float2bfloat16(acc[i][j][r]);
            }
        }
    }
}

// ---------------------------------------------------------------------------
// Per-channel sums/sumsq over 8192 rows for 4 Y tensors at once.
// grid 128 (64 rows each), block 256 (128 ch-threads x 2 row-threads), 8 ch/thread.
// sums layout: [4][2][1024] (sum then sumsq)
__global__ __launch_bounds__(256) void stats4_k(
    const bf16* __restrict__ Y0, const bf16* __restrict__ Y1,
    const bf16* __restrict__ Y2, const bf16* __restrict__ Y3,
    float* __restrict__ sums)
{
    int t = threadIdx.x;
    int ct = t & 127, rt = t >> 7;
    int ch0 = ct * 8;
    int rbase = blockIdx.x * 64 + rt;
    float s[4][8] = {}, q[4][8] = {};
    for (int it = 0; it < 32; it++) {
        size_t off = (size_t)(rbase + it * 2) * 1024 + ch0;
        bf16x8 y0 = *(const bf16x8*)(Y0 + off);
        bf16x8 y1 = *(const bf16x8*)(Y1 + off);
        bf16x8 y2 = *(const bf16x8*)(Y2 + off);
        bf16x8 y3 = *(const bf16x8*)(Y3 + off);
#pragma unroll
        for (int k = 0; k < 8; k++) {
            float v0 = __bfloat162float(y0.v[k]); s[0][k] += v0; q[0][k] += v0 * v0;
            float v1 = __bfloat162float(y1.v[k]); s[1][k] += v1; q[1][k] += v1 * v1;
            float v2 = __bfloat162float(y2.v[k]); s[2][k] += v2; q[2][k] += v2 * v2;
            float v3 = __bfloat162float(y3.v[k]); s[3][k] += v3; q[3][k] += v3 * v3;
        }
    }
#pragma unroll
    for (int br = 0; br < 4; br++)
#pragma unroll
        for (int k = 0; k < 8; k++) {
            atomicAdd(&sums[br * 2048 + ch0 + k], s[br][k]);
            atomicAdd(&sums[br * 2048 + 1024 + ch0 + k], q[br][k]);
        }
}

// Single-tensor variant (for Y4). sums: [2][1024]
__global__ __launch_bounds__(256) void stats1_k(const bf16* __restrict__ Y, float* __restrict__ sums)
{
    int t = threadIdx.x;
    int ct = t & 127, rt = t >> 7;
    int ch0 = ct * 8;
    int rbase = blockIdx.x * 64 + rt;
    float s[8] = {}, q[8] = {};
    for (int it = 0; it < 32; it++) {
        size_t off = (size_t)(rbase + it * 2) * 1024 + ch0;
        bf16x8 y = *(const bf16x8*)(Y + off);
#pragma unroll
        for (int k = 0; k < 8; k++) {
            float v = __bfloat162float(y.v[k]); s[k] += v; q[k] += v * v;
        }
    }
#pragma unroll
    for (int k = 0; k < 8; k++) {
        atomicAdd(&sums[ch0 + k], s[k]);
        atomicAdd(&sums[1024 + ch0 + k], q[k]);
    }
}

// ---------------------------------------------------------------------------
// sums -> per-channel scale/shift: sc = g * rsqrt(var+eps); sh = be - mu*sc
// (bias b cancels in y - mu, so it is never applied anywhere)
// ss layout: [5][2][1024]. grid (4, nslots), block 256.
__global__ void finalize_k(const float* __restrict__ sums, float* __restrict__ ss,
                           const float* g0, const float* be0, const float* g1, const float* be1,
                           const float* g2, const float* be2, const float* g3, const float* be3,
                           const float* g4, const float* be4, int slot0)
{
    int slot = slot0 + blockIdx.y;
    int ch = blockIdx.x * 256 + threadIdx.x;
    const float *g, *be;
    switch (slot) {
        case 0: g = g0; be = be0; break;
        case 1: g = g1; be = be1; break;
        case 2: g = g2; be = be2; break;
        case 3: g = g3; be = be3; break;
        default: g = g4; be = be4; break;
    }
    float sum = sums[slot * 2048 + ch];
    float sq  = sums[slot * 2048 + 1024 + ch];
    float mu  = sum * (1.f / 8192.f);
    float var = sq * (1.f / 8192.f) - mu * mu;
    float sc  = g[ch] * rsqrtf(var + EPSV);
    float sh  = be[ch] - mu * sc;
    ss[slot * 2048 + ch] = sc;
    ss[slot * 2048 + 1024 + ch] = sh;
}

// ---------------------------------------------------------------------------
// X4 = f4 + sum_i lrelu(Y_i * sc_i + sh_i).  Writes bf16 in-place over Y0 region
// (safe: each thread reads its 8 elements before writing the same addresses).
// grid 4096, block 256.
__global__ __launch_bounds__(256) void combine_k(
    const bf16* __restrict__ Y0, const bf16* __restrict__ Y1,
    const bf16* __restrict__ Y2, const bf16* __restrict__ Y3,
    const float* __restrict__ f4, const float* __restrict__ ss,
    bf16* __restrict__ X4)
{
    size_t base = ((size_t)blockIdx.x * 256 + threadIdx.x) * 8;
    int cq = (int)((base & 1023) >> 2);
    const floatx4* ssv = (const floatx4*)ss;
    floatx4 sc[4][2], sh[4][2];
#pragma unroll
    for (int br = 0; br < 4; br++) {
        sc[br][0] = ssv[br * 512 + cq];
        sc[br][1] = ssv[br * 512 + cq + 1];
        sh[br][0] = ssv[br * 512 + 256 + cq];
        sh[br][1] = ssv[br * 512 + 256 + cq + 1];
    }
    bf16x8 y0 = *(const bf16x8*)(Y0 + base);
    bf16x8 y1 = *(const bf16x8*)(Y1 + base);
    bf16x8 y2 = *(const bf16x8*)(Y2 + base);
    bf16x8 y3 = *(const bf16x8*)(Y3 + base);
    float4 v4a = ((const float4*)(f4 + base))[0];
    float4 v4b = ((const float4*)(f4 + base))[1];
    float v4[8] = {v4a.x, v4a.y, v4a.z, v4a.w, v4b.x, v4b.y, v4b.z, v4b.w};
    bf16x8 o;
#pragma unroll
    for (int k = 0; k < 8; k++) {
        int h = k >> 2, l = k & 3;
        float x = v4[k];
        x += lrelu(__bfloat162float(y0.v[k]) * sc[0][h][l] + sh[0][h][l]);
        x += lrelu(__bfloat162float(y1.v[k]) * sc[1][h][l] + sh[1][h][l]);
        x += lrelu(__bfloat162float(y2.v[k]) * sc[2][h][l] + sh[2][h][l]);
        x += lrelu(__bfloat162float(y3.v[k]) * sc[3][h][l] + sh[3][h][l]);
        o.v[k] = __float2bfloat16(x);
    }
    *(bf16x8*)(X4 + base) = o;
}

// ---------------------------------------------------------------------------
// out4 = lrelu(Y4 * sc + sh) + f4  (f32 out). grid 4096, block 256.
__global__ __launch_bounds__(256) void final_k(
    const bf16* __restrict__ Y4, const float* __restrict__ f4,
    const float* __restrict__ ss4, float* __restrict__ out4)
{
    size_t base = ((size_t)blockIdx.x * 256 + threadIdx.x) * 8;
    int cq = (int)((base & 1023) >> 2);
    const floatx4* ssv = (const floatx4*)ss4;
    floatx4 sc0 = ssv[cq], sc1 = ssv[cq + 1];
    floatx4 sh0 = ssv[256 + cq], sh1 = ssv[256 + cq + 1];
    bf16x8 y  = *(const bf16x8*)(Y4 + base);
    float4 v4a = ((const float4*)(f4 + base))[0];
    float4 v4b = ((const float4*)(f4 + base))[1];
    float v4[8] = {v4a.x, v4a.y, v4a.z, v4a.w, v4b.x, v4b.y, v4b.z, v4b.w};
    float o[8];
#pragma unroll
    for (int k = 0; k < 8; k++) {
        float sc = (k < 4) ? sc0[k & 3] : sc1[k & 3];
        float sh = (k < 4) ? sh0[k & 3] : sh1[k & 3];
        float v = __bfloat162float(y.v[k]) * sc + sh;
        o[k] = lrelu(v) + v4[k];
    }
    ((float4*)(out4 + base))[0] = make_float4(o[0], o[1], o[2], o[3]);
    ((float4*)(out4 + base))[1] = make_float4(o[4], o[5], o[6], o[7]);
}

// ---------------------------------------------------------------------------
extern "C" void kernel_launch(void* const* d_in, const int* in_sizes, int n_in,
                              void* d_out, int out_size, void* d_ws, size_t ws_size,
                              hipStream_t stream)
{
    // inputs: f32 tensors (per reference dtypes), int32 index arrays
    const float* f0 = (const float*)d_in[1];
    const float* f1 = (const float*)d_in[2];
    const float* f2 = (const float*)d_in[3];
    const float* f3 = (const float*)d_in[4];
    const float* f4 = (const float*)d_in[5];
    const int* FPS0 = (const int*)d_in[6];
    const int* FPS1 = (const int*)d_in[7];
    const int* FPS2 = (const int*)d_in[8];
    const int* FPS3 = (const int*)d_in[9];
    const float* w04 = (const float*)d_in[10];
    const float* g04 = (const float*)d_in[12];
    const float* be04 = (const float*)d_in[13];
    const float* w14 = (const float*)d_in[14];
    const float* g14 = (const float*)d_in[16];
    const float* be14 = (const float*)d_in[17];
    const float* w24 = (const float*)d_in[18];
    const float* g24 = (const float*)d_in[20];
    const float* be24 = (const float*)d_in[21];
    const float* w34 = (const float*)d_in[22];
    const float* g34 = (const float*)d_in[24];
    const float* be34 = (const float*)d_in[25];
    const float* w4 = (const float*)d_in[26];
    const float* g4 = (const float*)d_in[28];
    const float* be4 = (const float*)d_in[29];

    float* out = (float*)d_out;

    // workspace layout (~67 MiB): Y0..Y3 bf16, rowidx, sums, ss
    const size_t YN = (size_t)8192 * 1024;
    bf16* Y0 = (bf16*)d_ws;
    bf16* Y1 = Y0 + YN;
    bf16* Y2 = Y1 + YN;
    bf16* Y3 = Y2 + YN;
    int* rowidx = (int*)(Y3 + YN);             // [5][8192]
    float* sums = (float*)(rowidx + 5 * 8192); // [5][2][1024]
    float* ss = sums + 5 * 2048;               // [5][2][1024]
    bf16* X4 = Y0;   // alias: Y0 consumed elementwise before overwrite
    bf16* Y4 = Y1;   // alias: Y1 dead after combine

    if (ws_size < (size_t)(4 * YN * 2 + 5 * 8192 * 4 + 2 * 5 * 2048 * 4)) return;

    hipMemsetAsync(sums, 0, 5 * 2048 * sizeof(float), stream);

    copy4_k<<<dim3(4096, 4), 256, 0, stream>>>(f0, f1, f2, f3, out);
    idx_k<<<64, 128, 0, stream>>>(FPS0, FPS1, FPS2, FPS3, rowidx);

    gemm_bt<float><<<dim3(64, 8), 256, 0, stream>>>(f0, w04, Y0, rowidx + 0 * 8192, 64);
    gemm_bt<float><<<dim3(64, 8), 256, 0, stream>>>(f1, w14, Y1, rowidx + 1 * 8192, 128);
    gemm_bt<float><<<dim3(64, 8), 256, 0, stream>>>(f2, w24, Y2, rowidx + 2 * 8192, 256);
    gemm_bt<float><<<dim3(64, 8), 256, 0, stream>>>(f3, w34, Y3, rowidx + 3 * 8192, 512);

    stats4_k<<<128, 256, 0, stream>>>(Y0, Y1, Y2, Y3, sums);
    finalize_k<<<dim3(4, 4), 256, 0, stream>>>(sums, ss, g04, be04, g14, be14, g24, be24,
                                               g34, be34, g4, be4, 0);
    combine_k<<<4096, 256, 0, stream>>>(Y0, Y1, Y2, Y3, f4, ss, X4);

    gemm_bt<bf16><<<dim3(64, 8), 256, 0, stream>>>(X4, w4, Y4, rowidx + 4 * 8192, 1024);

    stats1_k<<<128, 256, 0, stream>>>(Y4, sums + 4 * 2048);
    finalize_k<<<dim3(4, 1), 256, 0, stream>>>(sums, ss, g04, be04, g14, be14, g24, be24,
                                               g34, be34, g4, be4, 4);
    final_k<<<4096, 256, 0, stream>>>(Y4, f4, ss + 4 * 2048, out + (size_t)4 * 8388608);
}

// Round 3
// 516.634 us; speedup vs baseline: 1.2582x; 1.2582x over previous
//
#include <hip/hip_runtime.h>
#include <hip/hip_bf16.h>
#include <type_traits>

using bf16 = __hip_bfloat16;
typedef __attribute__((ext_vector_type(8))) short short8;   // 8 bf16 = 4 VGPRs (A/B frag)
typedef __attribute__((ext_vector_type(4))) float floatx4;  // C/D frag

struct alignas(16) bf16x8 { bf16 v[8]; };

#define EPSV 1e-5f

__device__ __forceinline__ float lrelu(float v) { return v >= 0.f ? v : 0.2f * v; }

// convert 8 contiguous f32 -> 8 bf16 packed in a uint4
__device__ __forceinline__ uint4 f8_to_bf8(const float* __restrict__ p) {
    float4 a = ((const float4*)p)[0];
    float4 b = ((const float4*)p)[1];
    bf16x8 r;
    r.v[0] = __float2bfloat16(a.x); r.v[1] = __float2bfloat16(a.y);
    r.v[2] = __float2bfloat16(a.z); r.v[3] = __float2bfloat16(a.w);
    r.v[4] = __float2bfloat16(b.x); r.v[5] = __float2bfloat16(b.y);
    r.v[6] = __float2bfloat16(b.z); r.v[7] = __float2bfloat16(b.w);
    return *(uint4*)&r;
}

// ---------------------------------------------------------------------------
// Copy f0..f3 -> out regions 0..3 (bit-exact f32 passthrough). 8 f32/thread.
// grid (4096, 4), block 256
__global__ __launch_bounds__(256) void copy4_k(
    const float* __restrict__ f0, const float* __restrict__ f1,
    const float* __restrict__ f2, const float* __restrict__ f3,
    float* __restrict__ out)
{
    int region = blockIdx.y;
    const float* src = (region == 0) ? f0 : (region == 1) ? f1 : (region == 2) ? f2 : f3;
    size_t off = ((size_t)blockIdx.x * 256 + threadIdx.x) * 8;
    float* dst = out + (size_t)region * 8388608 + off;
    ((uint4*)dst)[0] = ((const uint4*)(src + off))[0];
    ((uint4*)dst)[1] = ((const uint4*)(src + off))[1];
}

// ---------------------------------------------------------------------------
// Index chains. grid 64, block 128.
// rowidx layout: [5][8192]; slots 0..3 = gathered row ids for f0..f3, slot 4 = identity.
__global__ void idx_k(const int* __restrict__ FPS0, const int* __restrict__ FPS1,
                      const int* __restrict__ FPS2, const int* __restrict__ FPS3,
                      int* __restrict__ rowidx)
{
    int b = blockIdx.x;    // 64
    int s = threadIdx.x;   // 128
    int i3 = FPS3[b * 128 + s];    // [0,256)
    int i2 = FPS2[b * 256 + i3];   // [0,512)
    int i1 = FPS1[b * 512 + i2];   // [0,1024)
    int i0 = FPS0[b * 1024 + i1];  // [0,2048)
    int m = b * 128 + s;
    rowidx[0 * 8192 + m] = b * 2048 + i0;
    rowidx[1 * 8192 + m] = b * 1024 + i1;
    rowidx[2 * 8192 + m] = b * 512 + i2;
    rowidx[3 * 8192 + m] = b * 256 + i3;
    rowidx[4 * 8192 + m] = m;
}

// ---------------------------------------------------------------------------
// GEMM: Y[m,n] = sum_k A[rowidx[m], k] * W[n, k]   (TN, both K-contiguous)
// with FUSED per-channel sum/sumsq reduction (BN batch stats) in the epilogue.
// A: f32 or bf16 [*, K] rows selected by rowidx; W: f32 [1024, K]; Y: bf16 [8192, 1024]
// f32 operands are converted to bf16 during LDS staging. Block 256 = 4 waves (2x2),
// tile 128x128, BK=32. grid (64, 8). sums: [2][1024] (sum, then sumsq), pre-zeroed.
template <typename AT>
__global__ __launch_bounds__(256) void gemm_bt(
    const AT* __restrict__ A, const float* __restrict__ W,
    bf16* __restrict__ Y, const int* __restrict__ rowidx, int K,
    float* __restrict__ sums)
{
    __shared__ bf16 As[128][40];   // +8 pad: stride 80B -> only 2-way bank alias (free)
    __shared__ bf16 Bs[128][40];

    int tid = threadIdx.x;
    int bm = blockIdx.x, bn = blockIdx.y;

    // staging assignments: each thread loads 2 rows x 8 elements per tile per operand
    int r0 = tid >> 2;               // 0..63
    int r1 = r0 + 64;                // 64..127
    int c0 = (tid & 3) << 3;         // 0,8,16,24 (elements)
    const AT* a0 = A + (size_t)rowidx[bm * 128 + r0] * K + c0;
    const AT* a1 = A + (size_t)rowidx[bm * 128 + r1] * K + c0;
    const float* b0 = W + (size_t)(bn * 128 + r0) * K + c0;
    const float* b1 = W + (size_t)(bn * 128 + r1) * K + c0;

    int lane = tid & 63, wave = tid >> 6;
    int wm = (wave >> 1) << 6;       // wave M origin within tile (0/64)
    int wn = (wave & 1) << 6;        // wave N origin within tile (0/64)
    int lm = lane & 15;              // A row / B col within 16-tile
    int kq = (lane >> 4) << 3;       // k quad offset (0/8/16/24)

    floatx4 acc[4][4] = {};

    for (int k0 = 0; k0 < K; k0 += 32) {
        if constexpr (std::is_same<AT, float>::value) {
            *(uint4*)&As[r0][c0] = f8_to_bf8(a0 + k0);
            *(uint4*)&As[r1][c0] = f8_to_bf8(a1 + k0);
        } else {
            *(uint4*)&As[r0][c0] = *(const uint4*)(a0 + k0);
            *(uint4*)&As[r1][c0] = *(const uint4*)(a1 + k0);
        }
        *(uint4*)&Bs[r0][c0] = f8_to_bf8(b0 + k0);
        *(uint4*)&Bs[r1][c0] = f8_to_bf8(b1 + k0);
        __syncthreads();

        short8 af[4], bfr[4];
#pragma unroll
        for (int i = 0; i < 4; i++) af[i]  = *(const short8*)&As[wm + i * 16 + lm][kq];
#pragma unroll
        for (int j = 0; j < 4; j++) bfr[j] = *(const short8*)&Bs[wn + j * 16 + lm][kq];
#pragma unroll
        for (int i = 0; i < 4; i++)
#pragma unroll
            for (int j = 0; j < 4; j++)
                acc[i][j] = __builtin_amdgcn_mfma_f32_16x16x32_bf16(af[i], bfr[j], acc[i][j], 0, 0, 0);
        __syncthreads();
    }

    // epilogue: C/D layout col=lane&15, row=quad*4+reg  (verified m89/m91)
    // Store Y (bf16) and accumulate per-channel sum/sumsq of the SAME bf16-rounded
    // values (what downstream kernels will read back).
    int mrow = (lane >> 4) << 2;
    int ncol = lane & 15;
    float ps[4] = {}, pq[4] = {};
#pragma unroll
    for (int i = 0; i < 4; i++) {
#pragma unroll
        for (int j = 0; j < 4; j++) {
#pragma unroll
            for (int r = 0; r < 4; r++) {
                int m = (bm << 7) + wm + i * 16 + mrow + r;
                int n = (bn << 7) + wn + j * 16 + ncol;
                bf16 bv = __float2bfloat16(acc[i][j][r]);
                Y[(size_t)m * 1024 + n] = bv;
                float v = __bfloat162float(bv);
                ps[j] += v; pq[j] += v * v;
            }
        }
    }
    // fold the 4 lanes that share a column (lane bits 4,5)
#pragma unroll
    for (int j = 0; j < 4; j++) {
        ps[j] += __shfl_xor(ps[j], 16); ps[j] += __shfl_xor(ps[j], 32);
        pq[j] += __shfl_xor(pq[j], 16); pq[j] += __shfl_xor(pq[j], 32);
    }
    if (lane < 16) {
#pragma unroll
        for (int j = 0; j < 4; j++) {
            int ch = (bn << 7) + wn + (j << 4) + lane;
            atomicAdd(&sums[ch], ps[j]);
            atomicAdd(&sums[1024 + ch], pq[j]);
        }
    }
}

// ---------------------------------------------------------------------------
// sums -> per-channel scale/shift: sc = g * rsqrt(var+eps); sh = be - mu*sc
// (bias b cancels in y - mu, so it is never applied anywhere)
// ss layout: [5][2][1024]. grid (4, nslots), block 256.
__global__ void finalize_k(const float* __restrict__ sums, float* __restrict__ ss,
                           const float* g0, const float* be0, const float* g1, const float* be1,
                           const float* g2, const float* be2, const float* g3, const float* be3,
                           const float* g4, const float* be4, int slot0)
{
    int slot = slot0 + blockIdx.y;
    int ch = blockIdx.x * 256 + threadIdx.x;
    const float *g, *be;
    switch (slot) {
        case 0: g = g0; be = be0; break;
        case 1: g = g1; be = be1; break;
        case 2: g = g2; be = be2; break;
        case 3: g = g3; be = be3; break;
        default: g = g4; be = be4; break;
    }
    float sum = sums[slot * 2048 + ch];
    float sq  = sums[slot * 2048 + 1024 + ch];
    float mu  = sum * (1.f / 8192.f);
    float var = sq * (1.f / 8192.f) - mu * mu;
    float sc  = g[ch] * rsqrtf(var + EPSV);
    float sh  = be[ch] - mu * sc;
    ss[slot * 2048 + ch] = sc;
    ss[slot * 2048 + 1024 + ch] = sh;
}

// ---------------------------------------------------------------------------
// X4 = f4 + sum_i lrelu(Y_i * sc_i + sh_i).  Writes bf16 in-place over Y0 region
// (safe: each thread reads its 8 elements before writing the same addresses).
// grid 4096, block 256.
__global__ __launch_bounds__(256) void combine_k(
    const bf16* __restrict__ Y0, const bf16* __restrict__ Y1,
    const bf16* __restrict__ Y2, const bf16* __restrict__ Y3,
    const float* __restrict__ f4, const float* __restrict__ ss,
    bf16* __restrict__ X4)
{
    size_t base = ((size_t)blockIdx.x * 256 + threadIdx.x) * 8;
    int cq = (int)((base & 1023) >> 2);
    const floatx4* ssv = (const floatx4*)ss;
    floatx4 sc[4][2], sh[4][2];
#pragma unroll
    for (int br = 0; br < 4; br++) {
        sc[br][0] = ssv[br * 512 + cq];
        sc[br][1] = ssv[br * 512 + cq + 1];
        sh[br][0] = ssv[br * 512 + 256 + cq];
        sh[br][1] = ssv[br * 512 + 256 + cq + 1];
    }
    bf16x8 y0 = *(const bf16x8*)(Y0 + base);
    bf16x8 y1 = *(const bf16x8*)(Y1 + base);
    bf16x8 y2 = *(const bf16x8*)(Y2 + base);
    bf16x8 y3 = *(const bf16x8*)(Y3 + base);
    float4 v4a = ((const float4*)(f4 + base))[0];
    float4 v4b = ((const float4*)(f4 + base))[1];
    float v4[8] = {v4a.x, v4a.y, v4a.z, v4a.w, v4b.x, v4b.y, v4b.z, v4b.w};
    bf16x8 o;
#pragma unroll
    for (int k = 0; k < 8; k++) {
        int h = k >> 2, l = k & 3;
        float x = v4[k];
        x += lrelu(__bfloat162float(y0.v[k]) * sc[0][h][l] + sh[0][h][l]);
        x += lrelu(__bfloat162float(y1.v[k]) * sc[1][h][l] + sh[1][h][l]);
        x += lrelu(__bfloat162float(y2.v[k]) * sc[2][h][l] + sh[2][h][l]);
        x += lrelu(__bfloat162float(y3.v[k]) * sc[3][h][l] + sh[3][h][l]);
        o.v[k] = __float2bfloat16(x);
    }
    *(bf16x8*)(X4 + base) = o;
}

// ---------------------------------------------------------------------------
// out4 = lrelu(Y4 * sc + sh) + f4  (f32 out). grid 4096, block 256.
__global__ __launch_bounds__(256) void final_k(
    const bf16* __restrict__ Y4, const float* __restrict__ f4,
    const float* __restrict__ ss4, float* __restrict__ out4)
{
    size_t base = ((size_t)blockIdx.x * 256 + threadIdx.x) * 8;
    int cq = (int)((base & 1023) >> 2);
    const floatx4* ssv = (const floatx4*)ss4;
    floatx4 sc0 = ssv[cq], sc1 = ssv[cq + 1];
    floatx4 sh0 = ssv[256 + cq], sh1 = ssv[256 + cq + 1];
    bf16x8 y  = *(const bf16x8*)(Y4 + base);
    float4 v4a = ((const float4*)(f4 + base))[0];
    float4 v4b = ((const float4*)(f4 + base))[1];
    float v4[8] = {v4a.x, v4a.y, v4a.z, v4a.w, v4b.x, v4b.y, v4b.z, v4b.w};
    float o[8];
#pragma unroll
    for (int k = 0; k < 8; k++) {
        float sc = (k < 4) ? sc0[k & 3] : sc1[k & 3];
        float sh = (k < 4) ? sh0[k & 3] : sh1[k & 3];
        float v = __bfloat162float(y.v[k]) * sc + sh;
        o[k] = lrelu(v) + v4[k];
    }
    ((float4*)(out4 + base))[0] = make_float4(o[0], o[1], o[2], o[3]);
    ((float4*)(out4 + base))[1] = make_float4(o[4], o[5], o[6], o[7]);
}

// ---------------------------------------------------------------------------
extern "C" void kernel_launch(void* const* d_in, const int* in_sizes, int n_in,
                              void* d_out, int out_size, void* d_ws, size_t ws_size,
                              hipStream_t stream)
{
    // inputs: f32 tensors (per reference dtypes), int32 index arrays
    const float* f0 = (const float*)d_in[1];
    const float* f1 = (const float*)d_in[2];
    const float* f2 = (const float*)d_in[3];
    const float* f3 = (const float*)d_in[4];
    const float* f4 = (const float*)d_in[5];
    const int* FPS0 = (const int*)d_in[6];
    const int* FPS1 = (const int*)d_in[7];
    const int* FPS2 = (const int*)d_in[8];
    const int* FPS3 = (const int*)d_in[9];
    const float* w04 = (const float*)d_in[10];
    const float* g04 = (const float*)d_in[12];
    const float* be04 = (const float*)d_in[13];
    const float* w14 = (const float*)d_in[14];
    const float* g14 = (const float*)d_in[16];
    const float* be14 = (const float*)d_in[17];
    const float* w24 = (const float*)d_in[18];
    const float* g24 = (const float*)d_in[20];
    const float* be24 = (const float*)d_in[21];
    const float* w34 = (const float*)d_in[22];
    const float* g34 = (const float*)d_in[24];
    const float* be34 = (const float*)d_in[25];
    const float* w4 = (const float*)d_in[26];
    const float* g4 = (const float*)d_in[28];
    const float* be4 = (const float*)d_in[29];

    float* out = (float*)d_out;

    // workspace layout (~67 MiB): Y0..Y3 bf16, rowidx, sums, ss
    const size_t YN = (size_t)8192 * 1024;
    bf16* Y0 = (bf16*)d_ws;
    bf16* Y1 = Y0 + YN;
    bf16* Y2 = Y1 + YN;
    bf16* Y3 = Y2 + YN;
    int* rowidx = (int*)(Y3 + YN);             // [5][8192]
    float* sums = (float*)(rowidx + 5 * 8192); // [5][2][1024]
    float* ss = sums + 5 * 2048;               // [5][2][1024]
    bf16* X4 = Y0;   // alias: Y0 consumed elementwise before overwrite
    bf16* Y4 = Y1;   // alias: Y1 dead after combine

    if (ws_size < (size_t)(4 * YN * 2 + 5 * 8192 * 4 + 2 * 5 * 2048 * 4)) return;

    hipMemsetAsync(sums, 0, 5 * 2048 * sizeof(float), stream);

    copy4_k<<<dim3(4096, 4), 256, 0, stream>>>(f0, f1, f2, f3, out);
    idx_k<<<64, 128, 0, stream>>>(FPS0, FPS1, FPS2, FPS3, rowidx);

    gemm_bt<float><<<dim3(64, 8), 256, 0, stream>>>(f0, w04, Y0, rowidx + 0 * 8192, 64,   sums + 0 * 2048);
    gemm_bt<float><<<dim3(64, 8), 256, 0, stream>>>(f1, w14, Y1, rowidx + 1 * 8192, 128,  sums + 1 * 2048);
    gemm_bt<float><<<dim3(64, 8), 256, 0, stream>>>(f2, w24, Y2, rowidx + 2 * 8192, 256,  sums + 2 * 2048);
    gemm_bt<float><<<dim3(64, 8), 256, 0, stream>>>(f3, w34, Y3, rowidx + 3 * 8192, 512,  sums + 3 * 2048);

    finalize_k<<<dim3(4, 4), 256, 0, stream>>>(sums, ss, g04, be04, g14, be14, g24, be24,
                                               g34, be34, g4, be4, 0);
    combine_k<<<4096, 256, 0, stream>>>(Y0, Y1, Y2, Y3, f4, ss, X4);

    gemm_bt<bf16><<<dim3(64, 8), 256, 0, stream>>>(X4, w4, Y4, rowidx + 4 * 8192, 1024, sums + 4 * 2048);

    finalize_k<<<dim3(4, 1), 256, 0, stream>>>(sums, ss, g04, be04, g14, be14, g24, be24,
                                               g34, be34, g4, be4, 4);
    final_k<<<4096, 256, 0, stream>>>(Y4, f4, ss + 4 * 2048, out + (size_t)4 * 8388608);
}